// Round 8
// baseline (218.041 us; speedup 1.0000x reference)
//
#include <hip/hip_runtime.h>

#define HID 64
#define TT  128
#define NROWS 8192
#define NGRP (NROWS / 8)    // 1024 blocks of 8 rows (2 waves x 4 rows); 4 blocks/CU
#define LOG2E 1.44269504088896f

typedef _Float16 half8 __attribute__((ext_vector_type(8)));
typedef float    f32x4 __attribute__((ext_vector_type(4)));

// ---------- pre-pass: length-sort rows into balanced 8-row groups ----------
// ws layout (ints): lens[8192] | perm[8192]

__global__ void k_len(const int* __restrict__ mask, int* __restrict__ lens) {
    const int row = blockIdx.x * 4 + (threadIdx.x >> 6);
    const int l   = threadIdx.x & 63;
    const int* mrow = mask + row * TT;
    int c = (mrow[l] != 0) + (mrow[l + 64] != 0);
    #pragma unroll
    for (int k = 32; k >= 1; k >>= 1) c += __shfl_xor(c, k);
    if (l == 0) lens[row] = c;
}

// Single block: LDS histogram -> prefix -> scatter. Descending rank d ->
// 8-row group g8 = d/8; slots {c, 511-c, 512+c, 1023-c} land on CU c.
__global__ __launch_bounds__(1024) void k_sort(const int* __restrict__ lens,
                                               int* __restrict__ perm) {
    __shared__ int hist[TT + 1];
    __shared__ int offs[TT + 1];
    const int tid = threadIdx.x;
    if (tid <= TT) hist[tid] = 0;
    __syncthreads();
    int myL[8];
    #pragma unroll
    for (int i = 0; i < 8; i++) {
        myL[i] = lens[tid + 1024 * i];
        atomicAdd(&hist[myL[i]], 1);
    }
    __syncthreads();
    if (tid <= TT) {
        int s = 0;
        for (int j = 0; j < tid; j++) s += hist[j];
        offs[tid] = s;
    }
    __syncthreads();
    #pragma unroll
    for (int i = 0; i < 8; i++) {
        const int pos = atomicAdd(&offs[myL[i]], 1);      // ascending rank
        const int d   = NROWS - 1 - pos;                  // descending rank
        const int g8  = d >> 3, r = d & 7;
        int b;
        if      (g8 < 256) b = g8;
        else if (g8 < 512) b = 256 + (511 - g8);
        else if (g8 < 768) b = 512 + (g8 - 512);
        else               b = 768 + (1023 - g8);
        perm[b * 8 + r] = tid + 1024 * i;
    }
}

// ---------- main GRU: barrier-free, j-complete waves, 4 rows/wave ----------
// Wave owns 4 rows and all 192 gates. MFMA cols = 4 rows x 4 reps; lane
// (u, cc): row cr4=cc&3 (+4*wid), rep=cc>>2 activates j = 16*rep+4u+{0..3}.
// h round-trips through wave-private LDS; NO in-loop __syncthreads.
__global__ __launch_bounds__(128, 2) void gru_fused(
    const int* __restrict__ actor_ids, const int* __restrict__ action_ids,
    const int* __restrict__ street_ids, const float* __restrict__ bet,
    const float* __restrict__ E_actor, const float* __restrict__ E_action,
    const float* __restrict__ E_street, const float* __restrict__ W_proj,
    const float* __restrict__ b_proj, const float* __restrict__ W_ih,
    const float* __restrict__ b_ih, const float* __restrict__ W_hh,
    const float* __restrict__ b_hh, const int* __restrict__ perm,
    const int* __restrict__ lens, float* __restrict__ out)
{
    __shared__ __align__(16) union {
        _Float16 wfs[192][32];                        // startup: fused W_f f16 (scaled)
        struct {
            int pb[TT][9];                            // ids|bet16, 8 rows + pad
            __align__(16) _Float16 hb[8][80];         // h, row stride 160B
            int Lsh[8];
            int Psh[8];
        } c;
    } A;
    __shared__ __align__(16) _Float16 embl[144];

    const int tid = threadIdx.x;
    const int wid = tid >> 6;        // wave 0: rows 0-3, wave 1: rows 4-7
    const int l   = tid & 63;
    const int u   = l >> 4;          // k-quad / D-row quad
    const int cc  = l & 15;          // MFMA col
    const int cr4 = cc & 3;          // row within wave
    const int rep = cc >> 2;         // replica -> owned j-block
    const int gr  = 4 * wid + cr4;   // row within block
    const int g   = blockIdx.x;

    // embedding rows: 0..6 actor, 7..10 action, 11..15 street(+pad), 16 zero
    for (int i = tid; i < 136; i += 128) {
        int r = i >> 3, m = i & 7;
        float v = 0.f;
        if (r < 7)       v = E_actor[r * 8 + m];
        else if (r < 11) v = E_action[(r - 7) * 8 + m];
        else if (r < 16) v = (m < 4) ? E_street[(r - 11) * 4 + m] : 0.f;
        embl[i] = (_Float16)v;
    }

    // ---- startup: fused input weights into LDS (f16, scaled); bias at k=21 ----
    // wfs[j][m] = (sum_k W_ih[j,k] W_proj[k,m]) * s; wfs[j][21] = total bias * s
    // (b_ih + W_ih b_proj, plus b_hh for r,z rows; b_hh(n) stays h-side).
    for (int j = tid; j < 192; j += 128) {
        float wf[21];
        #pragma unroll
        for (int m = 0; m < 21; m++) wf[m] = 0.f;
        float bf = b_ih[j];
        for (int k = 0; k < 32; k++) {
            const float w = W_ih[j * 32 + k];
            bf += w * b_proj[k];
            #pragma unroll
            for (int m = 0; m < 21; m++) wf[m] += w * W_proj[k * 21 + m];
        }
        if (j < 128) bf += b_hh[j];
        const float s = (j < 128) ? LOG2E : 2.f * LOG2E;
        #pragma unroll
        for (int m = 0; m < 21; m++) A.wfs[j][m] = (_Float16)(wf[m] * s);
        A.wfs[j][21] = (_Float16)(bf * s);
        #pragma unroll
        for (int m = 22; m < 32; m++) A.wfs[j][m] = (_Float16)0.f;
    }
    __syncthreads();

    // ---- per-lane fragments: Af[12], Ah[12][2], biasH[4] ----
    // A-layout: A[m=lane&15][k=(lane>>4)*8+pos]; tile jt = j 16jt..16jt+15.
    // Tiles 0-3 r, 4-7 z, 8-11 n.
    half8 Af[12], Ah[12][2];
    #pragma unroll
    for (int jt = 0; jt < 12; jt++) {
        const int jr = jt * 16 + cc;
        Af[jt] = *(const half8*)&A.wfs[jr][u * 8];
        const float s = (jt < 8) ? LOG2E : 2.f * LOG2E;
        #pragma unroll
        for (int kt = 0; kt < 2; kt++) {
            _Float16 w8[8];
            #pragma unroll
            for (int m = 0; m < 8; m++)
                w8[m] = (_Float16)(W_hh[jr * HID + kt * 32 + u * 8 + m] * s);
            Ah[jt][kt] = *(half8*)w8;
        }
    }
    f32x4 biasH[4];
    #pragma unroll
    for (int T = 0; T < 4; T++)
        #pragma unroll
        for (int e = 0; e < 4; e++)
            biasH[T][e] = b_hh[128 + 16 * T + 4 * u + e] * (2.f * LOG2E);
    __syncthreads();   // wfs dead; arena becomes pb/hb. LAST barrier.

    // ---- stage pb (each wave stages its OWN rows), lengths ----
    {
        const int r = tid >> 4, tl = tid & 15;       // wave0: r0-3, wave1: r4-7
        const int prow = perm[g * 8 + r];
        const int base = prow * TT;
        #pragma unroll
        for (int i = 0; i < 8; i++) {
            const int t = tl + 16 * i;
            const int a = actor_ids[base + t], c = action_ids[base + t];
            const int s = street_ids[base + t];
            const _Float16 f16 = (_Float16)bet[base + t];
            const unsigned fb = (unsigned)*(const unsigned short*)&f16;
            A.c.pb[t][r] = (int)(a | (c << 3) | (s << 5) | (fb << 16));
        }
        if (tl == 0) { A.c.Lsh[r] = lens[prow]; A.c.Psh[r] = prow; }
    }
    // no barrier: each wave reads only what it wrote (rows 4wid..4wid+3)

    const int Ln = A.c.Lsh[gr];
    int Lmax = Ln;                    // max over this wave's 4 rows (lane bits 0-1)
    { int o = __shfl_xor(Lmax, 1); Lmax = o > Lmax ? o : Lmax; }
    { int o = __shfl_xor(Lmax, 2); Lmax = o > Lmax ? o : Lmax; }

    // zero own h slot (4 f16 at j = 16rep+4u)
    _Float16* hbR = &A.c.hb[gr][0];
    *(uint2*)&hbR[16 * rep + 4 * u] = make_uint2(0u, 0u);

    const bool isu2 = (u == 2);
    const int sh = (u == 1) ? 3 : (u == 2) ? 5 : 0;
    const int mk = (u == 1) ? 3 : (u == 3) ? 0 : 7;
    const int of = (u == 1) ? 7 : (u == 2) ? 11 : (u == 3) ? 16 : 0;

    const f32x4 zero4 = {0.f, 0.f, 0.f, 0.f};
    float h[4] = {0.f, 0.f, 0.f, 0.f};

    // Bf pipeline: Bf holds step t, Bfn holds step t+1
    half8 Bf, Bfn;
    {
        const int p0 = A.c.pb[0][gr];
        Bf = *(const half8*)&embl[(((p0 >> sh) & mk) + of) * 8];
        uint4* b0 = (uint4*)&Bf;
        b0->z = isu2 ? (((unsigned)p0 >> 16) | 0x3C000000u) : b0->z; // {bet,1.0}
        const int p1 = A.c.pb[1][gr];
        Bfn = *(const half8*)&embl[(((p1 >> sh) & mk) + of) * 8];
        uint4* b1 = (uint4*)&Bfn;
        b1->z = isu2 ? (((unsigned)p1 >> 16) | 0x3C000000u) : b1->z;
    }

    for (int t = 0; t < Lmax; t++) {
        // h(t-1): wave-private LDS (in-order DS pipe; no barrier)
        const half8 Bh0 = *(const half8*)&hbR[8 * u];
        const half8 Bh1 = *(const half8*)&hbR[32 + 8 * u];
        const int t2 = (t + 2 < TT) ? t + 2 : TT - 1;
        const int p2 = A.c.pb[t2][gr];

        // x-side: 12 tiles, C=0 (biases ride feature 21)
        f32x4 x[12];
        #pragma unroll
        for (int jt = 0; jt < 12; jt++)
            x[jt] = __builtin_amdgcn_mfma_f32_16x16x32_f16(Af[jt], Bf, zero4, 0, 0, 0);
        // h-side r,z: chained through x-acc
        f32x4 acc[8];
        #pragma unroll
        for (int jt = 0; jt < 8; jt++) {
            f32x4 t0 = __builtin_amdgcn_mfma_f32_16x16x32_f16(Ah[jt][0], Bh0, x[jt], 0, 0, 0);
            acc[jt]  = __builtin_amdgcn_mfma_f32_16x16x32_f16(Ah[jt][1], Bh1, t0, 0, 0, 0);
        }
        // h-side n: C = b_hh(n) (inside r*(.))
        f32x4 hn[4];
        #pragma unroll
        for (int T = 0; T < 4; T++) {
            f32x4 t0 = __builtin_amdgcn_mfma_f32_16x16x32_f16(Ah[8 + T][0], Bh0, biasH[T], 0, 0, 0);
            hn[T]    = __builtin_amdgcn_mfma_f32_16x16x32_f16(Ah[8 + T][1], Bh1, t0, 0, 0, 0);
        }

        // gather Bf(t+2) under MFMA/activation latency
        half8 Bf2;
        {
            Bf2 = *(const half8*)&embl[(((p2 >> sh) & mk) + of) * 8];
            uint4* b2 = (uint4*)&Bf2;
            b2->z = isu2 ? (((unsigned)p2 >> 16) | 0x3C000000u) : b2->z;
        }

        // select this lane's j-block (tile = rep) per gate
        const f32x4 aR  = rep < 2 ? (rep == 0 ? acc[0] : acc[1]) : (rep == 2 ? acc[2] : acc[3]);
        const f32x4 aZ  = rep < 2 ? (rep == 0 ? acc[4] : acc[5]) : (rep == 2 ? acc[6] : acc[7]);
        const f32x4 xn  = rep < 2 ? (rep == 0 ? x[8]   : x[9])   : (rep == 2 ? x[10]  : x[11]);
        const f32x4 hnv = rep < 2 ? (rep == 0 ? hn[0]  : hn[1])  : (rep == 2 ? hn[2]  : hn[3]);

        const bool live = (t < Ln);
        _Float16 hp[4];
        #pragma unroll
        for (int e = 0; e < 4; e++) {
            const float r = __builtin_amdgcn_rcpf(1.f + __builtin_amdgcn_exp2f(-aR[e]));
            const float z = __builtin_amdgcn_rcpf(1.f + __builtin_amdgcn_exp2f(-aZ[e]));
            const float y2 = xn[e] + r * hnv[e];          // 2*log2e*y
            const float nn = 1.f - 2.f * __builtin_amdgcn_rcpf(1.f + __builtin_amdgcn_exp2f(y2));
            const float hv = nn + z * (h[e] - nn);
            h[e] = live ? hv : h[e];
            hp[e] = (_Float16)h[e];
        }
        *(uint2*)&hbR[16 * rep + 4 * u] = *(uint2*)hp;   // own contiguous j-block

        Bf = Bfn; Bfn = Bf2;
    }

    const int prow = A.c.Psh[gr];
    *(float4*)&out[prow * HID + 16 * rep + 4 * u] = make_float4(h[0], h[1], h[2], h[3]);
}

extern "C" void kernel_launch(void* const* d_in, const int* in_sizes, int n_in,
                              void* d_out, int out_size, void* d_ws, size_t ws_size,
                              hipStream_t stream) {
    const int*   actor_ids  = (const int*)d_in[0];
    const int*   action_ids = (const int*)d_in[1];
    const int*   street_ids = (const int*)d_in[2];
    const float* bet        = (const float*)d_in[3];
    const int*   vmask      = (const int*)d_in[4];
    const float* E_actor    = (const float*)d_in[5];
    const float* E_action   = (const float*)d_in[6];
    const float* E_street   = (const float*)d_in[7];
    const float* W_proj     = (const float*)d_in[8];
    const float* b_proj     = (const float*)d_in[9];
    const float* W_ih       = (const float*)d_in[10];
    const float* W_hh       = (const float*)d_in[11];
    const float* b_ih       = (const float*)d_in[12];
    const float* b_hh       = (const float*)d_in[13];
    float*       out        = (float*)d_out;

    int* ws   = (int*)d_ws;
    int* lens = ws;
    int* perm = ws + NROWS;

    k_len<<<NROWS / 4, 256, 0, stream>>>(vmask, lens);
    k_sort<<<1, 1024, 0, stream>>>(lens, perm);

    gru_fused<<<NGRP, 128, 0, stream>>>(actor_ids, action_ids, street_ids, bet,
                                        E_actor, E_action, E_street,
                                        W_proj, b_proj, W_ih, b_ih, W_hh, b_hh,
                                        perm, lens, out);
}